// Round 10
// baseline (21.329 us; speedup 1.0000x reference)
//
#include <hip/hip_runtime.h>
#include <hip/hip_fp16.h>
#include <math.h>

#define MM 8192
#define NN 64
#define NB 25
#define MPB 8               // m's per block
#define PPT 2               // points per thread
#define KS 12               // floats per K record (10 used, 48B stride)
#define LOG2E 1.44269504088896340736f

struct Q { float w, x, y, z; };
typedef float f32x2 __attribute__((ext_vector_type(2)));

__device__ __forceinline__ Q qmul(const Q a, const Q b) {
    Q r;
    r.w = a.w*b.w - a.x*b.x - a.y*b.y - a.z*b.z;
    r.x = a.w*b.x + b.w*a.x + a.y*b.z - a.z*b.y;
    r.y = a.w*b.y + b.w*a.y + a.z*b.x - a.x*b.z;
    r.z = a.w*b.z + b.w*a.z + a.x*b.y - a.y*b.x;
    return r;
}

__device__ __forceinline__ unsigned pk_rn(float a, float b) {
    return __builtin_bit_cast(unsigned, __floats2half2_rn(a, b));
}
typedef __fp16 f16x2 __attribute__((ext_vector_type(2)));
__device__ __forceinline__ __half2 pk_rtz(float a, float b) {
    f16x2 v = __builtin_amdgcn_cvt_pkrtz(a, b);
    return __builtin_bit_cast(__half2, v);
}
__device__ __forceinline__ __half2 bc_h2(unsigned u) {
    return __builtin_bit_cast(__half2, u);
}

// ---- prep: 25 quadratic-form records (rest row 0 + log_gauss only), 1 tiny block ----
__global__ __launch_bounds__(64) void prep_kernel(
    const float* __restrict__ rest_qr, const float* __restrict__ rest_qd,
    const float* __restrict__ log_gauss, float* __restrict__ Kbuf)
{
    const int b = threadIdx.x;
    if (b >= NB) return;
    const float4 Rqv = *reinterpret_cast<const float4*>(rest_qr + b * 4);
    const float4 Rdv = *reinterpret_cast<const float4*>(rest_qd + b * 4);
    const Q Rq{Rqv.x, Rqv.y, Rqv.z, Rqv.w};
    const Q Rqc{Rq.w, -Rq.x, -Rq.y, -Rq.z};
    const Q Rdc{Rdv.x, -Rdv.y, -Rdv.z, -Rdv.w};
    const float i0 = __expf(-log_gauss[b * 3 + 0]);
    const float i1 = __expf(-log_gauss[b * 3 + 1]);
    const float i2 = __expf(-log_gauss[b * 3 + 2]);
    const Q tqb = qmul(Rdc, Rq);
    const float qw = Rqc.w, qx = Rqc.x, qy = Rqc.y, qz = Rqc.z;
    const float r00 = 1.f - 2.f*(qy*qy + qz*qz), r01 = 2.f*(qx*qy - qw*qz), r02 = 2.f*(qx*qz + qw*qy);
    const float r10 = 2.f*(qx*qy + qw*qz), r11 = 1.f - 2.f*(qx*qx + qz*qz), r12 = 2.f*(qy*qz - qw*qx);
    const float r20 = 2.f*(qx*qz - qw*qy), r21 = 2.f*(qy*qz + qw*qx), r22 = 1.f - 2.f*(qx*qx + qy*qy);
    const float g00 = r00*i0, g01 = r01*i0, g02 = r02*i0;
    const float g10 = r10*i1, g11 = r11*i1, g12 = r12*i1;
    const float g20 = r20*i2, g21 = r21*i2, g22 = r22*i2;
    const float u0 = 2.f*tqb.x*i0, u1 = 2.f*tqb.y*i1, u2 = 2.f*tqb.z*i2;
    const float c = LOG2E;
    float* kp = Kbuf + b * KS;
    *reinterpret_cast<float4*>(kp + 0) = make_float4(
        -0.5f*c*(g00*g00 + g10*g10 + g20*g20),
        -0.5f*c*(g01*g01 + g11*g11 + g21*g21),
        -0.5f*c*(g02*g02 + g12*g12 + g22*g22),
        -c*(g00*g01 + g10*g11 + g20*g21));
    *reinterpret_cast<float4*>(kp + 4) = make_float4(
        -c*(g00*g02 + g10*g12 + g20*g22),
        -c*(g01*g02 + g11*g12 + g21*g22),
        -c*(g00*u0 + g10*u1 + g20*u2),
        -c*(g01*u0 + g11*u1 + g21*u2));
    *reinterpret_cast<float4*>(kp + 8) = make_float4(
        -c*(g02*u0 + g12*u1 + g22*u2),
        -0.5f*c*(u0*u0 + u1*u1 + u2*u2), 0.f, 0.f);
}

// ---- skin: pass 1 = SMEM-only kK, pass 2 = DS-only qQ; 4 waves/SIMD ----
__global__ __launch_bounds__(256, 4) void skin_kernel(
    const float* __restrict__ xyz,
    const float* __restrict__ t_qr,
    const float* __restrict__ t_qd,
    const float* __restrict__ rest_qr,
    const float* __restrict__ rest_qd,
    const float* __restrict__ Kb,
    float* __restrict__ out)
{
    __shared__ __align__(16) float    sref[MPB][4];       // bone-0 se_r per m
    __shared__ __align__(16) unsigned qQ[MPB][NB][4];     // packed fp16 (qr,qd) per (m,b)

    const int t  = threadIdx.x;
    const int m0 = blockIdx.x * MPB;

    // -------- early xyz loads (VMEM, overlaps phase 1) --------
    const int m_sub = t >> 5;                  // 32 threads per m
    const int pt0   = (t & 31) * PPT;
    const int pbase = ((m0 + m_sub) * NN + pt0) * 3;
    const float2 a0 = *reinterpret_cast<const float2*>(xyz + pbase);
    const float2 a1 = *reinterpret_cast<const float2*>(xyz + pbase + 2);
    const float2 a2 = *reinterpret_cast<const float2*>(xyz + pbase + 4);

    // -------- phase 1: se3 records (8 m x 25 = 200 threads) --------
    Q se_r{0,0,0,0}, se_d{0,0,0,0};
    int ms = 0, bb = 0;
    const bool act = t < MPB * NB;
    if (act) {
        ms = t / NB; bb = t - ms * NB;
        const int gbase = (m0 * NB + t) * 4;
        const float4 Tqv = *reinterpret_cast<const float4*>(t_qr + gbase);
        const float4 Tdv = *reinterpret_cast<const float4*>(t_qd + gbase);
        const float4 Rqv = *reinterpret_cast<const float4*>(rest_qr + bb * 4);
        const float4 Rdv = *reinterpret_cast<const float4*>(rest_qd + bb * 4);
        const Q Tq{Tqv.x, Tqv.y, Tqv.z, Tqv.w};
        const Q Td{Tdv.x, Tdv.y, Tdv.z, Tdv.w};
        const Q Rq{Rqv.x, Rqv.y, Rqv.z, Rqv.w};
        const Q Rqc{Rq.w, -Rq.x, -Rq.y, -Rq.z};
        const Q Rdc{Rdv.x, -Rdv.y, -Rdv.z, -Rdv.w};
        se_r = qmul(Tq, Rqc);
        const Q a1q = qmul(Tq, Rdc);
        const Q a2q = qmul(Td, Rqc);
        se_d = Q{a1q.w + a2q.w, a1q.x + a2q.x, a1q.y + a2q.y, a1q.z + a2q.z};
        if (bb == 0) *reinterpret_cast<float4*>(sref[ms]) = make_float4(se_r.w, se_r.x, se_r.y, se_r.z);
    }
    __syncthreads();
    if (act) {
        const float4 rf = *reinterpret_cast<const float4*>(sref[ms]);
        const float d0 = se_r.w*rf.x + se_r.x*rf.y + se_r.y*rf.z + se_r.z*rf.w;
        const float sg = (d0 < 0.f) ? -1.f : 1.f;
        qQ[ms][bb][0] = pk_rn(sg*se_r.w, sg*se_r.x);
        qQ[ms][bb][1] = pk_rn(sg*se_r.y, sg*se_r.z);
        qQ[ms][bb][2] = pk_rn(sg*se_d.w, sg*se_d.x);
        qQ[ms][bb][3] = pk_rn(sg*se_d.y, sg*se_d.z);
    }
    __syncthreads();

    // -------- pass 1: logits via s_load'ed kK, packed f32x2 over 2 points --------
    const f32x2 pxv = {a0.x, a1.y};
    const f32x2 pyv = {a0.y, a2.x};
    const f32x2 pzv = {a1.x, a2.y};
    const f32x2 fxx = pxv*pxv, fyy = pyv*pyv, fzz = pzv*pzv;
    const f32x2 fxy = pxv*pyv, fxz = pxv*pzv, fyz = pyv*pzv;

    f32x2 lg[NB];
    f32x2 mx = {-3.4e38f, -3.4e38f};
#pragma unroll
    for (int b = 0; b < NB; ++b) {
        const float k0 = Kb[b*KS+0], k1 = Kb[b*KS+1], k2 = Kb[b*KS+2], k3 = Kb[b*KS+3], k4 = Kb[b*KS+4];
        const float k5 = Kb[b*KS+5], k6 = Kb[b*KS+6], k7 = Kb[b*KS+7], k8 = Kb[b*KS+8], k9 = Kb[b*KS+9];
        f32x2 s = {k9, k9};
        s = __builtin_elementwise_fma((f32x2){k8,k8}, pzv, s);
        s = __builtin_elementwise_fma((f32x2){k7,k7}, pyv, s);
        s = __builtin_elementwise_fma((f32x2){k6,k6}, pxv, s);
        s = __builtin_elementwise_fma((f32x2){k5,k5}, fyz, s);
        s = __builtin_elementwise_fma((f32x2){k4,k4}, fxz, s);
        s = __builtin_elementwise_fma((f32x2){k3,k3}, fxy, s);
        s = __builtin_elementwise_fma((f32x2){k2,k2}, fzz, s);
        s = __builtin_elementwise_fma((f32x2){k1,k1}, fyy, s);
        s = __builtin_elementwise_fma((f32x2){k0,k0}, fxx, s);
        lg[b] = s;
        mx = __builtin_elementwise_max(mx, s);
    }

    // -------- pass 2: blend via ds_read'ed qQ (unnormalized; denominator cancels) --------
    const __half2 hz = __floats2half2_rn(0.f, 0.f);
    __half2 acc00 = hz, acc01 = hz, acc02 = hz, acc03 = hz;
    __half2 acc10 = hz, acc11 = hz, acc12 = hz, acc13 = hz;

#pragma unroll
    for (int b = 0; b < NB; ++b) {
        const uint4 qv = *reinterpret_cast<const uint4*>(&qQ[m_sub][b][0]);  // 1x ds_read_b128
        const __half2 h0 = bc_h2(qv.x), h1 = bc_h2(qv.y), h2 = bc_h2(qv.z), h3 = bc_h2(qv.w);
        const f32x2 d = lg[b] - mx;
        const float e0 = __builtin_amdgcn_exp2f(d.x);
        const float e1 = __builtin_amdgcn_exp2f(d.y);
        const __half2 e20 = pk_rtz(e0, e0);
        const __half2 e21 = pk_rtz(e1, e1);
        acc00 = __hfma2(e20, h0, acc00);
        acc01 = __hfma2(e20, h1, acc01);
        acc02 = __hfma2(e20, h2, acc02);
        acc03 = __hfma2(e20, h3, acc03);
        acc10 = __hfma2(e21, h0, acc10);
        acc11 = __hfma2(e21, h1, acc11);
        acc12 = __hfma2(e21, h2, acc12);
        acc13 = __hfma2(e21, h3, acc13);
    }

    // -------- epilogue --------
    const float px[PPT] = {pxv.x, pxv.y};
    const float py[PPT] = {pyv.x, pyv.y};
    const float pz[PPT] = {pzv.x, pzv.y};
    __half2 accs[PPT][4] = {{acc00, acc01, acc02, acc03}, {acc10, acc11, acc12, acc13}};
    float o[PPT*3];
#pragma unroll
    for (int p = 0; p < PPT; ++p) {
        const float aw = __low2float(accs[p][0]), ax = __high2float(accs[p][0]);
        const float ay = __low2float(accs[p][1]), az = __high2float(accs[p][1]);
        const float bw = __low2float(accs[p][2]), bx = __high2float(accs[p][2]);
        const float by = __low2float(accs[p][3]), bz = __high2float(accs[p][3]);

        const float inv = rsqrtf(aw*aw + ax*ax + ay*ay + az*az);
        const Q qr{aw*inv, ax*inv, ay*inv, az*inv};
        const Q qd{bw*inv, bx*inv, by*inv, bz*inv};
        const Q qrc{qr.w, -qr.x, -qr.y, -qr.z};
        const Q tq = qmul(qd, qrc);

        const float uvx = qr.y*pz[p] - qr.z*py[p];
        const float uvy = qr.z*px[p] - qr.x*pz[p];
        const float uvz = qr.x*py[p] - qr.y*px[p];
        const float cx = qr.y*uvz - qr.z*uvy;
        const float cy = qr.z*uvx - qr.x*uvz;
        const float cz = qr.x*uvy - qr.y*uvx;

        o[p*3+0] = px[p] + 2.f*(qr.w*uvx + cx) + 2.f*tq.x;
        o[p*3+1] = py[p] + 2.f*(qr.w*uvy + cy) + 2.f*tq.y;
        o[p*3+2] = pz[p] + 2.f*(qr.w*uvz + cz) + 2.f*tq.z;
    }

    *reinterpret_cast<float2*>(out + pbase)     = make_float2(o[0], o[1]);
    *reinterpret_cast<float2*>(out + pbase + 2) = make_float2(o[2], o[3]);
    *reinterpret_cast<float2*>(out + pbase + 4) = make_float2(o[4], o[5]);
}

extern "C" void kernel_launch(void* const* d_in, const int* in_sizes, int n_in,
                              void* d_out, int out_size, void* d_ws, size_t ws_size,
                              hipStream_t stream) {
    const float* xyz       = (const float*)d_in[0];
    const float* t_qr      = (const float*)d_in[1];
    const float* t_qd      = (const float*)d_in[2];
    const float* rest_qr   = (const float*)d_in[3];
    const float* rest_qd   = (const float*)d_in[4];
    const float* log_gauss = (const float*)d_in[5];
    float* out  = (float*)d_out;
    float* Kbuf = (float*)d_ws;    // 25*12*4 = 1200 B

    hipLaunchKernelGGL(prep_kernel, dim3(1), dim3(64), 0, stream,
                       rest_qr, rest_qd, log_gauss, Kbuf);
    hipLaunchKernelGGL(skin_kernel, dim3(MM / MPB), dim3(256), 0, stream,
                       xyz, t_qr, t_qd, rest_qr, rest_qd, Kbuf, out);
}

// Round 11
// 15.198 us; speedup vs baseline: 1.4034x; 1.4034x over previous
//
#include <hip/hip_runtime.h>
#include <hip/hip_fp16.h>
#include <math.h>

#define MM 8192
#define NN 64
#define NB 25
#define MPB 8               // m's per block
#define PPT 2               // points per thread
#define LOG2E 1.44269504088896340736f

struct Q { float w, x, y, z; };
typedef float f32x2 __attribute__((ext_vector_type(2)));

__device__ __forceinline__ Q qmul(const Q a, const Q b) {
    Q r;
    r.w = a.w*b.w - a.x*b.x - a.y*b.y - a.z*b.z;
    r.x = a.w*b.x + b.w*a.x + a.y*b.z - a.z*b.y;
    r.y = a.w*b.y + b.w*a.y + a.z*b.x - a.x*b.z;
    r.z = a.w*b.z + b.w*a.z + a.x*b.y - a.y*b.x;
    return r;
}

__device__ __forceinline__ unsigned pk_rn(float a, float b) {
    return __builtin_bit_cast(unsigned, __floats2half2_rn(a, b));
}
typedef __fp16 f16x2 __attribute__((ext_vector_type(2)));
__device__ __forceinline__ __half2 pk_rtz(float a, float b) {
    f16x2 v = __builtin_amdgcn_cvt_pkrtz(a, b);
    return __builtin_bit_cast(__half2, v);
}
__device__ __forceinline__ __half2 bc_h2(unsigned u) {
    return __builtin_bit_cast(__half2, u);
}

__global__ __launch_bounds__(256, 4) void skin_kernel(
    const float* __restrict__ xyz,
    const float* __restrict__ t_qr,
    const float* __restrict__ t_qd,
    const float* __restrict__ rest_qr,
    const float* __restrict__ rest_qd,
    const float* __restrict__ log_gauss,
    float* __restrict__ out)
{
    __shared__ __align__(16) float4   kK4[NB][3];         // packed quadratic-form coeffs
    __shared__ __align__(16) float    sref[MPB][4];       // bone-0 se_r per m
    __shared__ __align__(16) unsigned qQ[MPB][NB][4];     // packed fp16 (qr,qd) per (m,b)

    const int t  = threadIdx.x;
    const int m0 = blockIdx.x * MPB;

    // -------- early xyz loads (VMEM, overlaps prep phases) --------
    const int m_sub = t >> 5;                  // 32 threads per m
    const int pt0   = (t & 31) * PPT;
    const int pbase = ((m0 + m_sub) * NN + pt0) * 3;
    const float2 a0 = *reinterpret_cast<const float2*>(xyz + pbase);
    const float2 a1 = *reinterpret_cast<const float2*>(xyz + pbase + 2);
    const float2 a2 = *reinterpret_cast<const float2*>(xyz + pbase + 4);

    // -------- phase 0: K table (rest row 0 + log_gauss only), threads 0..24 --------
    if (t < NB) {
        const int b = t;
        const float4 Rqv = *reinterpret_cast<const float4*>(rest_qr + b * 4);
        const float4 Rdv = *reinterpret_cast<const float4*>(rest_qd + b * 4);
        const Q Rq{Rqv.x, Rqv.y, Rqv.z, Rqv.w};
        const Q Rqc{Rq.w, -Rq.x, -Rq.y, -Rq.z};
        const Q Rdc{Rdv.x, -Rdv.y, -Rdv.z, -Rdv.w};
        const float i0 = __expf(-log_gauss[b * 3 + 0]);
        const float i1 = __expf(-log_gauss[b * 3 + 1]);
        const float i2 = __expf(-log_gauss[b * 3 + 2]);
        const Q tqb = qmul(Rdc, Rq);
        const float qw = Rqc.w, qx = Rqc.x, qy = Rqc.y, qz = Rqc.z;
        const float r00 = 1.f - 2.f*(qy*qy + qz*qz), r01 = 2.f*(qx*qy - qw*qz), r02 = 2.f*(qx*qz + qw*qy);
        const float r10 = 2.f*(qx*qy + qw*qz), r11 = 1.f - 2.f*(qx*qx + qz*qz), r12 = 2.f*(qy*qz - qw*qx);
        const float r20 = 2.f*(qx*qz - qw*qy), r21 = 2.f*(qy*qz + qw*qx), r22 = 1.f - 2.f*(qx*qx + qy*qy);
        const float g00 = r00*i0, g01 = r01*i0, g02 = r02*i0;
        const float g10 = r10*i1, g11 = r11*i1, g12 = r12*i1;
        const float g20 = r20*i2, g21 = r21*i2, g22 = r22*i2;
        const float u0 = 2.f*tqb.x*i0, u1 = 2.f*tqb.y*i1, u2 = 2.f*tqb.z*i2;
        const float c = LOG2E;
        kK4[b][0] = make_float4(
            -0.5f*c*(g00*g00 + g10*g10 + g20*g20),
            -0.5f*c*(g01*g01 + g11*g11 + g21*g21),
            -0.5f*c*(g02*g02 + g12*g12 + g22*g22),
            -c*(g00*g01 + g10*g11 + g20*g21));
        kK4[b][1] = make_float4(
            -c*(g00*g02 + g10*g12 + g20*g22),
            -c*(g01*g02 + g11*g12 + g21*g22),
            -c*(g00*u0 + g10*u1 + g20*u2),
            -c*(g01*u0 + g11*u1 + g21*u2));
        kK4[b][2] = make_float4(
            -c*(g02*u0 + g12*u1 + g22*u2),
            -0.5f*c*(u0*u0 + u1*u1 + u2*u2), 0.f, 0.f);
    }

    // -------- phase 1: se3 records (8 m x 25 = 200 threads) --------
    Q se_r{0,0,0,0}, se_d{0,0,0,0};
    int ms = 0, bb = 0;
    const bool act = t < MPB * NB;
    if (act) {
        ms = t / NB; bb = t - ms * NB;
        const int gbase = (m0 * NB + t) * 4;
        const float4 Tqv = *reinterpret_cast<const float4*>(t_qr + gbase);
        const float4 Tdv = *reinterpret_cast<const float4*>(t_qd + gbase);
        const float4 Rqv = *reinterpret_cast<const float4*>(rest_qr + bb * 4);
        const float4 Rdv = *reinterpret_cast<const float4*>(rest_qd + bb * 4);
        const Q Tq{Tqv.x, Tqv.y, Tqv.z, Tqv.w};
        const Q Td{Tdv.x, Tdv.y, Tdv.z, Tdv.w};
        const Q Rq{Rqv.x, Rqv.y, Rqv.z, Rqv.w};
        const Q Rqc{Rq.w, -Rq.x, -Rq.y, -Rq.z};
        const Q Rdc{Rdv.x, -Rdv.y, -Rdv.z, -Rdv.w};
        se_r = qmul(Tq, Rqc);
        const Q a1q = qmul(Tq, Rdc);
        const Q a2q = qmul(Td, Rqc);
        se_d = Q{a1q.w + a2q.w, a1q.x + a2q.x, a1q.y + a2q.y, a1q.z + a2q.z};
        if (bb == 0) *reinterpret_cast<float4*>(sref[ms]) = make_float4(se_r.w, se_r.x, se_r.y, se_r.z);
    }
    __syncthreads();
    if (act) {
        const float4 rf = *reinterpret_cast<const float4*>(sref[ms]);
        const float d0 = se_r.w*rf.x + se_r.x*rf.y + se_r.y*rf.z + se_r.z*rf.w;
        const float sg = (d0 < 0.f) ? -1.f : 1.f;
        qQ[ms][bb][0] = pk_rn(sg*se_r.w, sg*se_r.x);
        qQ[ms][bb][1] = pk_rn(sg*se_r.y, sg*se_r.z);
        qQ[ms][bb][2] = pk_rn(sg*se_d.w, sg*se_d.x);
        qQ[ms][bb][3] = pk_rn(sg*se_d.y, sg*se_d.z);
    }
    __syncthreads();

    // -------- pass 1: logits from packed kK (3x ds_read_b128 per bone), f32x2 pk-math --------
    const f32x2 pxv = {a0.x, a1.y};
    const f32x2 pyv = {a0.y, a2.x};
    const f32x2 pzv = {a1.x, a2.y};
    const f32x2 fxx = pxv*pxv, fyy = pyv*pyv, fzz = pzv*pzv;
    const f32x2 fxy = pxv*pyv, fxz = pxv*pzv, fyz = pyv*pzv;

    f32x2 lg[NB];
    f32x2 mx = {-3.4e38f, -3.4e38f};
#pragma unroll
    for (int b = 0; b < NB; ++b) {
        const float4 c0 = kK4[b][0];
        const float4 c1 = kK4[b][1];
        const float4 c2 = kK4[b][2];
        f32x2 s = {c2.y, c2.y};
        s = __builtin_elementwise_fma((f32x2){c2.x,c2.x}, pzv, s);
        s = __builtin_elementwise_fma((f32x2){c1.w,c1.w}, pyv, s);
        s = __builtin_elementwise_fma((f32x2){c1.z,c1.z}, pxv, s);
        s = __builtin_elementwise_fma((f32x2){c1.y,c1.y}, fyz, s);
        s = __builtin_elementwise_fma((f32x2){c1.x,c1.x}, fxz, s);
        s = __builtin_elementwise_fma((f32x2){c0.w,c0.w}, fxy, s);
        s = __builtin_elementwise_fma((f32x2){c0.z,c0.z}, fzz, s);
        s = __builtin_elementwise_fma((f32x2){c0.y,c0.y}, fyy, s);
        s = __builtin_elementwise_fma((f32x2){c0.x,c0.x}, fxx, s);
        lg[b] = s;
        mx = __builtin_elementwise_max(mx, s);
    }

    // -------- pass 2: blend via qQ (1x ds_read_b128 per bone), fp16 accumulate --------
    const __half2 hz = __floats2half2_rn(0.f, 0.f);
    __half2 acc00 = hz, acc01 = hz, acc02 = hz, acc03 = hz;
    __half2 acc10 = hz, acc11 = hz, acc12 = hz, acc13 = hz;

#pragma unroll
    for (int b = 0; b < NB; ++b) {
        const uint4 qv = *reinterpret_cast<const uint4*>(&qQ[m_sub][b][0]);
        const __half2 h0 = bc_h2(qv.x), h1 = bc_h2(qv.y), h2 = bc_h2(qv.z), h3 = bc_h2(qv.w);
        const f32x2 d = lg[b] - mx;
        const float e0 = __builtin_amdgcn_exp2f(d.x);
        const float e1 = __builtin_amdgcn_exp2f(d.y);
        const __half2 e20 = pk_rtz(e0, e0);
        const __half2 e21 = pk_rtz(e1, e1);
        acc00 = __hfma2(e20, h0, acc00);
        acc01 = __hfma2(e20, h1, acc01);
        acc02 = __hfma2(e20, h2, acc02);
        acc03 = __hfma2(e20, h3, acc03);
        acc10 = __hfma2(e21, h0, acc10);
        acc11 = __hfma2(e21, h1, acc11);
        acc12 = __hfma2(e21, h2, acc12);
        acc13 = __hfma2(e21, h3, acc13);
    }

    // -------- epilogue --------
    const float px[PPT] = {pxv.x, pxv.y};
    const float py[PPT] = {pyv.x, pyv.y};
    const float pz[PPT] = {pzv.x, pzv.y};
    const __half2 accs[PPT][4] = {{acc00, acc01, acc02, acc03}, {acc10, acc11, acc12, acc13}};
    float o[PPT*3];
#pragma unroll
    for (int p = 0; p < PPT; ++p) {
        const float aw = __low2float(accs[p][0]), ax = __high2float(accs[p][0]);
        const float ay = __low2float(accs[p][1]), az = __high2float(accs[p][1]);
        const float bw = __low2float(accs[p][2]), bx = __high2float(accs[p][2]);
        const float by = __low2float(accs[p][3]), bz = __high2float(accs[p][3]);

        const float inv = rsqrtf(aw*aw + ax*ax + ay*ay + az*az);
        const Q qr{aw*inv, ax*inv, ay*inv, az*inv};
        const Q qd{bw*inv, bx*inv, by*inv, bz*inv};
        const Q qrc{qr.w, -qr.x, -qr.y, -qr.z};
        const Q tq = qmul(qd, qrc);

        const float uvx = qr.y*pz[p] - qr.z*py[p];
        const float uvy = qr.z*px[p] - qr.x*pz[p];
        const float uvz = qr.x*py[p] - qr.y*px[p];
        const float cx = qr.y*uvz - qr.z*uvy;
        const float cy = qr.z*uvx - qr.x*uvz;
        const float cz = qr.x*uvy - qr.y*uvx;

        o[p*3+0] = px[p] + 2.f*(qr.w*uvx + cx) + 2.f*tq.x;
        o[p*3+1] = py[p] + 2.f*(qr.w*uvy + cy) + 2.f*tq.y;
        o[p*3+2] = pz[p] + 2.f*(qr.w*uvz + cz) + 2.f*tq.z;
    }

    *reinterpret_cast<float2*>(out + pbase)     = make_float2(o[0], o[1]);
    *reinterpret_cast<float2*>(out + pbase + 2) = make_float2(o[2], o[3]);
    *reinterpret_cast<float2*>(out + pbase + 4) = make_float2(o[4], o[5]);
}

extern "C" void kernel_launch(void* const* d_in, const int* in_sizes, int n_in,
                              void* d_out, int out_size, void* d_ws, size_t ws_size,
                              hipStream_t stream) {
    const float* xyz       = (const float*)d_in[0];
    const float* t_qr      = (const float*)d_in[1];
    const float* t_qd      = (const float*)d_in[2];
    const float* rest_qr   = (const float*)d_in[3];
    const float* rest_qd   = (const float*)d_in[4];
    const float* log_gauss = (const float*)d_in[5];
    float* out = (float*)d_out;

    hipLaunchKernelGGL(skin_kernel, dim3(MM / MPB), dim3(256), 0, stream,
                       xyz, t_qr, t_qd, rest_qr, rest_qd, log_gauss, out);
}